// Round 8
// baseline (269.462 us; speedup 1.0000x reference)
//
#include <hip/hip_runtime.h>
#include <stdint.h>

#define EPS 1e-5f

typedef short v8s __attribute__((ext_vector_type(8)));
typedef float v4f __attribute__((ext_vector_type(4)));

// ---------------- ws float layout ----------------
//  [0,4)     absmax {c1,c2,f1,f2}
//  16/80/144/208    c1 sum/ssq/scale/shift (64 each)
//  272/400/528/656  c2 sum/ssq/scale/shift (128 each)
//  784 fc scale(512) 1296 fc shift(512)  1808 fc sum(512) 2320 fc ssq(512)
//  W1F  = 4096    : conv1 weights float [k=25][c=64]        (1600 f)
//  W2F  = 8192    : conv2 weights bf16 MFMA-frag order      (204800 us)
//  WF2F = 212992  : fc2 weights float [j][512]              (5120 f)
//  A_F  = 262144  : PMN fp32 [512][128][16][2]{max,min} (2097152 f),
//                   later fc1out fp32 [512,512] (256K f, PMN dead)
//  B_F  = 19136512: pool1 bf16 NHWC [512][144][64];
//                   later pool2 bf16 B-frag (1048576 us, pool1 dead)
//  WF1T = B_F + 1048576 : fc1 weights bf16 A-frag (1048576 us)
static const size_t W1F  = 4096;
static const size_t W2F  = 8192;
static const size_t WF2F = 212992;
static const size_t A_F  = 262144;
static const size_t B_F  = 19136512;
static const size_t WF1T = B_F + 1048576;

__device__ inline unsigned short f2bf(float f) {
    unsigned u = __float_as_uint(f);
    return (unsigned short)((u + 0x7FFF + ((u >> 16) & 1)) >> 16);
}

__global__ void k_zero(float* p, int n) {
    int i = blockIdx.x * blockDim.x + threadIdx.x;
    if (i < n) p[i] = 0.f;
}

// 4 absmax reductions in one launch (fc1_w gets 192 blocks)
__global__ void k_absmax4(const float* __restrict__ w0, int n0,
                          const float* __restrict__ w1, int n1,
                          const float* __restrict__ w2, int n2,
                          const float* __restrict__ w3, int n3,
                          float* outv) {
    int blk = blockIdx.x;
    const float* w; int n; unsigned* out; int nb; int bi;
    if (blk < 1)        { w = w0; n = n0; out = (unsigned*)(outv + 0); nb = 1;   bi = blk;      }
    else if (blk < 17)  { w = w1; n = n1; out = (unsigned*)(outv + 1); nb = 16;  bi = blk - 1;  }
    else if (blk < 209) { w = w2; n = n2; out = (unsigned*)(outv + 2); nb = 192; bi = blk - 17; }
    else                { w = w3; n = n3; out = (unsigned*)(outv + 3); nb = 1;   bi = blk - 209; }
    float m = 0.f;
    for (int i = bi * 256 + threadIdx.x; i < n; i += nb * 256)
        m = fmaxf(m, fabsf(w[i]));
    #pragma unroll
    for (int o = 32; o; o >>= 1) m = fmaxf(m, __shfl_down(m, o));
    if ((threadIdx.x & 63) == 0) atomicMax(out, __float_as_uint(m));
}

// quantize: conv1 -> w1t float [k=25][c=64]; conv2 -> bf16 A-frag order; fc2 float
// conv2 frag: idx = ((p*2+ks)*8 + mt)*512 + lane*8 + j
//   = Q(conv2_w[c][ci][p]), c = mt*16 + (lane&15), ci = ks*32 + (lane>>4)*8 + j
__global__ void k_quantE(const float* __restrict__ c1w, const float* __restrict__ c2w,
                         const float* __restrict__ f2w, const float* __restrict__ am,
                         float* __restrict__ w1t, unsigned short* __restrict__ w2u,
                         float* __restrict__ wf2) {
    int blk = blockIdx.x;
    if (blk < 1) {
        float t = 0.05f * am[0];
        for (int i = threadIdx.x; i < 1600; i += 256) {
            float v = c1w[i];
            float q = (float)((v > t) - (v < -t));
            int c = i / 25, k = i - c * 25;
            w1t[k * 64 + c] = q;
        }
    } else if (blk < 101) {
        float t = 0.05f * am[1];
        int base = (blk - 1) * 2048;
        #pragma unroll
        for (int jj = 0; jj < 8; ++jj) {
            int i = base + jj * 256 + threadIdx.x;
            int j    = i & 7;
            int lane = (i >> 3) & 63;
            int mt   = (i >> 9) & 7;
            int ks   = (i >> 12) & 1;
            int p    = i >> 13;
            int c  = mt * 16 + (lane & 15);
            int ci = ks * 32 + (lane >> 4) * 8 + j;
            float v = c2w[c * 1600 + ci * 25 + p];
            w2u[i] = (v > t) ? (unsigned short)0x3F80
                             : ((v < -t) ? (unsigned short)0xBF80 : (unsigned short)0);
        }
    } else {
        float t = 0.05f * am[3];
        for (int i = threadIdx.x; i < 5120; i += 256) {
            float v = f2w[i];
            wf2[i] = (float)((v > t) - (v < -t));
        }
    }
}

// fc1 quantize -> bf16 A-frag: idx = ((ks*32 + ft)*64 + lane)*8 + j
//   = Q(fc1_w[f][k]), f = ft*16 + (lane&15), k = ks*32 + (lane>>4)*8 + j
__global__ void k_quantF1(const float* __restrict__ w, const float* __restrict__ am,
                          unsigned short* __restrict__ wf) {
    float t = 0.05f * am[2];
    int i = blockIdx.x * 256 + threadIdx.x;
    int j    = i & 7;
    int lane = (i >> 3) & 63;
    int ft   = (i >> 9) & 31;
    int ks   = i >> 14;
    int f = ft * 16 + (lane & 15);
    int k = ks * 32 + (lane >> 4) * 8 + j;
    float v = w[f * 2048 + k];
    wf[i] = (v > t) ? (unsigned short)0x3F80
                    : ((v < -t) ? (unsigned short)0xBF80 : (unsigned short)0);
}

// conv1 pass A: stats only. Block per image, 512 threads; lane = out channel.
__global__ __launch_bounds__(512) void k_conv1A(const float* __restrict__ x,
                                                const float* __restrict__ w1t,
                                                float* __restrict__ sum,
                                                float* __restrict__ ssq) {
    __shared__ float xs[784];
    __shared__ float red[2][8][64];
    int b = blockIdx.x;
    const float4* xim = (const float4*)(x + (size_t)b * 784);
    for (int i = threadIdx.x; i < 196; i += 512) ((float4*)xs)[i] = xim[i];
    int c  = threadIdx.x & 63;
    int wv = threadIdx.x >> 6;
    float w[25];
    #pragma unroll
    for (int k = 0; k < 25; ++k) w[k] = w1t[k * 64 + c];
    __syncthreads();
    float s = 0.f, s2 = 0.f;
    int oh = 0, ow = wv;
    for (int it = 0; it < 72; ++it) {
        const float* xp = xs + oh * 28 + ow;
        float acc = 0.f;
        #pragma unroll
        for (int kh = 0; kh < 5; ++kh)
            #pragma unroll
            for (int kw = 0; kw < 5; ++kw)
                acc = fmaf(xp[kh * 28 + kw], w[kh * 5 + kw], acc);
        s += acc; s2 += acc * acc;
        ow += 8; if (ow >= 24) { ow -= 24; ++oh; }
    }
    red[0][wv][c] = s; red[1][wv][c] = s2;
    __syncthreads();
    if (threadIdx.x < 64) {
        float S = 0.f, S2 = 0.f;
        #pragma unroll
        for (int i = 0; i < 8; ++i) { S += red[0][i][threadIdx.x]; S2 += red[1][i][threadIdx.x]; }
        atomicAdd(&sum[threadIdx.x], S);
        atomicAdd(&ssq[threadIdx.x], S2);
    }
}

// conv1 pass B: recompute conv1 + bn + relu + pool -> pool1 NHWC bf16 [b][144][64]
__global__ __launch_bounds__(512) void k_conv1B(const float* __restrict__ x,
                                                const float* __restrict__ w1t,
                                                const float* __restrict__ scale,
                                                const float* __restrict__ shift,
                                                unsigned short* __restrict__ pool1) {
    __shared__ float xs[784];
    int b = blockIdx.x;
    const float4* xim = (const float4*)(x + (size_t)b * 784);
    for (int i = threadIdx.x; i < 196; i += 512) ((float4*)xs)[i] = xim[i];
    int c  = threadIdx.x & 63;
    int wv = threadIdx.x >> 6;
    float w[25];
    #pragma unroll
    for (int k = 0; k < 25; ++k) w[k] = w1t[k * 64 + c];
    float sc = scale[c], sh = shift[c];
    __syncthreads();
    unsigned short* ob = pool1 + (size_t)b * 9216;
    int ph = 0, pw = wv;
    for (int it = 0; it < 18; ++it) {
        const float* xp = xs + (ph * 2) * 28 + pw * 2;
        float win[36];
        #pragma unroll
        for (int i = 0; i < 6; ++i)
            #pragma unroll
            for (int j = 0; j < 6; ++j) win[i * 6 + j] = xp[i * 28 + j];
        float v00 = 0.f, v01 = 0.f, v10 = 0.f, v11 = 0.f;
        #pragma unroll
        for (int i = 0; i < 5; ++i)
            #pragma unroll
            for (int j = 0; j < 5; ++j) {
                float wk = w[i * 5 + j];
                v00 = fmaf(win[i * 6 + j],           wk, v00);
                v01 = fmaf(win[i * 6 + j + 1],       wk, v01);
                v10 = fmaf(win[(i + 1) * 6 + j],     wk, v10);
                v11 = fmaf(win[(i + 1) * 6 + j + 1], wk, v11);
            }
        float r0 = fmaxf(0.f, fmaf(v00, sc, sh));
        float r1 = fmaxf(0.f, fmaf(v01, sc, sh));
        float r2 = fmaxf(0.f, fmaf(v10, sc, sh));
        float r3 = fmaxf(0.f, fmaf(v11, sc, sh));
        ob[(ph * 12 + pw) * 64 + c] = f2bf(fmaxf(fmaxf(r0, r1), fmaxf(r2, r3)));
        pw += 8; if (pw >= 12) { pw -= 12; ++ph; }
    }
}

// conv2 MFMA v4: barrier-free K-loop. Block per image, 4 waves.
// Wave = M=32 (2 mt tiles), N=64 (4 bfrags shared across mt).
// Weights stream global->VGPR with 3-deep register prefetch (no LDS, no barriers).
// Fused bn2 stats + 2x2 maxpool (stores {max,min} pairs).
__global__ __launch_bounds__(256) void k_conv2(const unsigned short* __restrict__ pool1,
                                               const unsigned short* __restrict__ wfrag,
                                               float* __restrict__ pmn,
                                               float* __restrict__ sum,
                                               float* __restrict__ ssq) {
    __shared__ unsigned short xs[144 * 72];    // 20736 B, ldci=72 pad
    int b    = blockIdx.x;
    int tid  = threadIdx.x;
    int lane = tid & 63;
    int w    = tid >> 6;                       // M-quarter
    const unsigned short* src = pool1 + (size_t)b * 9216;
    for (int i = tid; i < 1152; i += 256) {
        int r = i >> 3, part = i & 7;
        *(float4*)(&xs[r * 72 + part * 8]) = *(const float4*)(src + r * 64 + part * 8);
    }
    int n = lane & 15, quad = lane >> 4;
    int ow = n & 7, ohp = n >> 3;
    const unsigned short* wbase = wfrag + (size_t)(w * 2) * 512 + lane * 8;
    v8s pf[4][2];
    #pragma unroll
    for (int s = 0; s < 3; ++s) {
        pf[s][0] = *(const v8s*)(wbase + (size_t)(s * 8) * 512);
        pf[s][1] = *(const v8s*)(wbase + (size_t)(s * 8 + 1) * 512);
    }
    __syncthreads();                           // the only barrier
    v4f acc[2][4];
    #pragma unroll
    for (int mm = 0; mm < 2; ++mm)
        #pragma unroll
        for (int q = 0; q < 4; ++q) acc[mm][q] = (v4f){0.f, 0.f, 0.f, 0.f};
    int kh = 0, kw = 0;
    #pragma unroll
    for (int step = 0; step < 50; ++step) {
        if (step + 3 < 50) {
            pf[(step + 3) & 3][0] = *(const v8s*)(wbase + (size_t)((step + 3) * 8) * 512);
            pf[(step + 3) & 3][1] = *(const v8s*)(wbase + (size_t)((step + 3) * 8 + 1) * 512);
        }
        int ks = step & 1;
        int colo = (ow + kw) * 72 + ks * 32 + quad * 8;
        #pragma unroll
        for (int q = 0; q < 4; ++q) {
            v8s bf = *(const v8s*)(&xs[(q * 2 + ohp + kh) * 864 + colo]);  // 12*72=864
            acc[0][q] = __builtin_amdgcn_mfma_f32_16x16x32_bf16(pf[step & 3][0], bf, acc[0][q], 0, 0, 0);
            acc[1][q] = __builtin_amdgcn_mfma_f32_16x16x32_bf16(pf[step & 3][1], bf, acc[1][q], 0, 0, 0);
        }
        if (ks) { ++kw; if (kw == 5) { kw = 0; ++kh; } }
    }
    // epilogue: pooled {max,min} + per-channel stats, no cross-wave sharing needed
    float* po = pmn + (size_t)b * 4096;        // [128][16][2]
    #pragma unroll
    for (int mm = 0; mm < 2; ++mm) {
        #pragma unroll
        for (int r = 0; r < 4; ++r) {
            int c = w * 32 + mm * 16 + quad * 4 + r;
            float sA = 0.f, s2A = 0.f;
            #pragma unroll
            for (int q = 0; q < 4; ++q) {
                float v = acc[mm][q][r];
                float pm = fmaxf(v, __shfl_xor(v, 1));
                float pn = fminf(v, __shfl_xor(v, 1));
                pm = fmaxf(pm, __shfl_xor(pm, 8));
                pn = fminf(pn, __shfl_xor(pn, 8));
                if (((n & 1) == 0) && (n < 8)) {
                    int psp = q * 4 + (n >> 1);
                    *(float2*)(&po[(c * 16 + psp) * 2]) = make_float2(pm, pn);
                }
                float s = v, s2 = v * v;
                #pragma unroll
                for (int m = 1; m < 16; m <<= 1) { s += __shfl_xor(s, m); s2 += __shfl_xor(s2, m); }
                sA += s; s2A += s2;
            }
            if (n == 0) { atomicAdd(&sum[c], sA); atomicAdd(&ssq[c], s2A); }
        }
    }
}

__global__ void k_finalize(const float* __restrict__ sum, const float* __restrict__ ssq,
                           const float* __restrict__ g, const float* __restrict__ bt,
                           float* __restrict__ scale, float* __restrict__ shift,
                           int C, float invN) {
    int c = blockIdx.x * blockDim.x + threadIdx.x;
    if (c >= C) return;
    float mean = sum[c] * invN;
    float var  = ssq[c] * invN - mean * mean;
    float sc   = g[c] * rsqrtf(var + EPS);
    scale[c] = sc;
    shift[c] = bt[c] - mean * sc;
}

// bn2+relu on pooled pairs -> pool2 bf16 in fc1 B-frag order
__global__ void k_bnpool2(const float* __restrict__ pmn, const float* __restrict__ scale,
                          const float* __restrict__ shift, unsigned short* __restrict__ xfrag) {
    int i = blockIdx.x * 256 + threadIdx.x;    // 1048576
    int j    = i & 7;
    int lane = (i >> 3) & 63;
    int bt   = (i >> 9) & 31;
    int ks   = i >> 14;
    int b = bt * 16 + (lane & 15);
    int k = ks * 32 + (lane >> 4) * 8 + j;
    int c = k >> 4, psp = k & 15;
    float2 mm = *(const float2*)(&pmn[((size_t)b * 2048 + c * 16 + psp) * 2]);
    float sc = scale[c], sh = shift[c];
    float v = (sc > 0.f) ? mm.x : mm.y;
    xfrag[i] = f2bf(fmaxf(0.f, fmaf(v, sc, sh)));
}

// fc1 MFMA: fused bn3 stats. Grid 128: blockIdx = bT*4 + ftg; wave -> 2 f-tiles.
__global__ __launch_bounds__(256) void k_fc1(const unsigned short* __restrict__ xfrag,
                                             const unsigned short* __restrict__ wfrag,
                                             float* __restrict__ out,
                                             float* __restrict__ sum,
                                             float* __restrict__ ssq) {
    int lane = threadIdx.x & 63;
    int wave = threadIdx.x >> 6;
    int fB = (blockIdx.x & 3) * 8 + wave * 2;
    int bT = blockIdx.x >> 2;
    v4f acc[2];
    acc[0] = (v4f){0,0,0,0}; acc[1] = (v4f){0,0,0,0};
    for (int ks = 0; ks < 64; ++ks) {
        v8s bfrag = *(const v8s*)(xfrag + ((size_t)(ks * 32 + bT) * 64 + lane) * 8);
        #pragma unroll
        for (int mt = 0; mt < 2; ++mt) {
            v8s afrag = *(const v8s*)(wfrag + ((size_t)(ks * 32 + fB + mt) * 64 + lane) * 8);
            acc[mt] = __builtin_amdgcn_mfma_f32_16x16x32_bf16(afrag, bfrag, acc[mt], 0, 0, 0);
        }
    }
    int bb = bT * 16 + (lane & 15);
    int quad = lane >> 4;
    #pragma unroll
    for (int mt = 0; mt < 2; ++mt) {
        int f0 = (fB + mt) * 16 + quad * 4;
        *(float4*)(&out[(size_t)bb * 512 + f0]) =
            make_float4(acc[mt][0], acc[mt][1], acc[mt][2], acc[mt][3]);
        #pragma unroll
        for (int r = 0; r < 4; ++r) {
            float s = acc[mt][r], s2 = s * s;
            #pragma unroll
            for (int m = 1; m < 16; m <<= 1) { s += __shfl_xor(s, m); s2 += __shfl_xor(s2, m); }
            if ((lane & 15) == 0) { atomicAdd(&sum[f0 + r], s); atomicAdd(&ssq[f0 + r], s2); }
        }
    }
}

// fc2 with fused bn3+relu: wave per batch row; lane-parallel float4 loads.
__global__ __launch_bounds__(256) void k_fc2(const float* __restrict__ x,
                                             const float* __restrict__ w,
                                             const float* __restrict__ bias,
                                             const float* __restrict__ scale,
                                             const float* __restrict__ shift,
                                             float* __restrict__ out) {
    int lane = threadIdx.x & 63;
    int b = blockIdx.x * 4 + (threadIdx.x >> 6);
    const float4* xp = (const float4*)(x + (size_t)b * 512 + lane * 8);
    const float4* scp = (const float4*)(scale + lane * 8);
    const float4* shp = (const float4*)(shift + lane * 8);
    float4 x0 = xp[0], x1 = xp[1];
    float4 s0 = scp[0], s1 = scp[1];
    float4 h0 = shp[0], h1 = shp[1];
    float h[8];
    h[0] = fmaxf(0.f, fmaf(x0.x, s0.x, h0.x));
    h[1] = fmaxf(0.f, fmaf(x0.y, s0.y, h0.y));
    h[2] = fmaxf(0.f, fmaf(x0.z, s0.z, h0.z));
    h[3] = fmaxf(0.f, fmaf(x0.w, s0.w, h0.w));
    h[4] = fmaxf(0.f, fmaf(x1.x, s1.x, h1.x));
    h[5] = fmaxf(0.f, fmaf(x1.y, s1.y, h1.y));
    h[6] = fmaxf(0.f, fmaf(x1.z, s1.z, h1.z));
    h[7] = fmaxf(0.f, fmaf(x1.w, s1.w, h1.w));
    #pragma unroll
    for (int j = 0; j < 10; ++j) {
        const float4* wp = (const float4*)(w + j * 512 + lane * 8);
        float4 w0 = wp[0], w1 = wp[1];
        float p = h[0] * w0.x + h[1] * w0.y + h[2] * w0.z + h[3] * w0.w
                + h[4] * w1.x + h[5] * w1.y + h[6] * w1.z + h[7] * w1.w;
        #pragma unroll
        for (int o = 32; o; o >>= 1) p += __shfl_down(p, o);
        if (lane == 0) out[b * 10 + j] = p + bias[j];
    }
}

extern "C" void kernel_launch(void* const* d_in, const int* in_sizes, int n_in,
                              void* d_out, int out_size, void* d_ws, size_t ws_size,
                              hipStream_t stream) {
    const float* x       = (const float*)d_in[0];
    const float* conv1_w = (const float*)d_in[1];
    const float* bn1_g   = (const float*)d_in[3];
    const float* bn1_b   = (const float*)d_in[4];
    const float* conv2_w = (const float*)d_in[5];
    const float* bn2_g   = (const float*)d_in[7];
    const float* bn2_b   = (const float*)d_in[8];
    const float* fc1_w   = (const float*)d_in[9];
    const float* bn3_g   = (const float*)d_in[11];
    const float* bn3_b   = (const float*)d_in[12];
    const float* fc2_w   = (const float*)d_in[13];
    const float* fc2_b   = (const float*)d_in[14];
    // conv1_b / conv2_b / fc1_b are absorbed by train-mode BN

    float* wsf = (float*)d_ws;

    float* c1_sum = wsf + 16,   * c1_ssq = wsf + 80;
    float* c1_sc  = wsf + 144,  * c1_sh  = wsf + 208;
    float* c2_sum = wsf + 272,  * c2_ssq = wsf + 400;
    float* c2_sc  = wsf + 528,  * c2_sh  = wsf + 656;
    float* f_sc   = wsf + 784,  * f_sh   = wsf + 1296;
    float* f_sum  = wsf + 1808, * f_ssq  = wsf + 2320;

    float* w1t = wsf + W1F;
    unsigned short* w2u = (unsigned short*)(wsf + W2F);
    float* wf2 = wsf + WF2F;
    unsigned short* wf1 = (unsigned short*)(wsf + WF1T);
    float* PMN = wsf + A_F;                          // [512][128][16][2]
    float* A   = wsf + A_F;                          // fc1out (PMN dead by then)
    unsigned short* pool1 = (unsigned short*)(wsf + B_F);
    unsigned short* xfrag = (unsigned short*)(wsf + B_F);

    // zero stats (absmax + all sums)
    k_zero<<<16, 256, 0, stream>>>(wsf, 4096);

    // absmax (all 4 tensors)
    k_absmax4<<<210, 256, 0, stream>>>(conv1_w, 1600, conv2_w, 204800,
                                       fc1_w, 1048576, fc2_w, 5120, wsf);

    // quantize conv1 / conv2 (MFMA-frag bf16) / fc2
    k_quantE<<<102, 256, 0, stream>>>(conv1_w, conv2_w, fc2_w, wsf, w1t, w2u, wf2);

    // conv1 pass A: stats only
    k_conv1A<<<512, 512, 0, stream>>>(x, w1t, c1_sum, c1_ssq);
    k_finalize<<<1, 64, 0, stream>>>(c1_sum, c1_ssq, bn1_g, bn1_b, c1_sc, c1_sh, 64,
                                     1.f / 294912.f);

    // conv1 pass B: recompute + bn + relu + pool -> pool1 NHWC bf16
    k_conv1B<<<512, 512, 0, stream>>>(x, w1t, c1_sc, c1_sh, pool1);

    // conv2 MFMA v4 (barrier-free, register weight prefetch) -> PMN
    k_conv2<<<512, 256, 0, stream>>>(pool1, w2u, PMN, c2_sum, c2_ssq);

    // fc1 weights -> bf16 A-frag (pool1 now dead)
    k_quantF1<<<4096, 256, 0, stream>>>(fc1_w, wsf, wf1);

    k_finalize<<<1, 128, 0, stream>>>(c2_sum, c2_ssq, bn2_g, bn2_b, c2_sc, c2_sh, 128,
                                      1.f / 32768.f);

    // bn2+relu on pooled pairs -> pool2 bf16 B-frag
    k_bnpool2<<<4096, 256, 0, stream>>>(PMN, c2_sc, c2_sh, xfrag);

    // fc1 MFMA (fused bn3 stats) -> A fp32 [512,512]
    k_fc1<<<128, 256, 0, stream>>>(xfrag, wf1, A, f_sum, f_ssq);
    k_finalize<<<2, 256, 0, stream>>>(f_sum, f_ssq, bn3_g, bn3_b, f_sc, f_sh, 512,
                                      1.f / 512.f);

    // fc2 (fused bn3+relu) -> d_out [512,10]
    k_fc2<<<128, 256, 0, stream>>>(A, wf2, fc2_b, f_sc, f_sh, (float*)d_out);
}